// Round 1
// 74.391 us; speedup vs baseline: 1.2478x; 1.2478x over previous
//
#include <hip/hip_runtime.h>

// Path signature, depth 4: B=32, L=1024, d=8, fp32.
// Levels: S1(8) S2(64) S3(512) S4(4096); sig stride 4680 floats.
//
// R19 = R15/R18 structure (measured optimum 92.8us) with the chunk loop
// slimmed for issue count (it is issue-bound at 1 wave/SIMD):
//   - increments precomputed into LDS at staging time: kills the 10 v_sub +
//     10 v_mov per step of (nm-cm)/rotate bookkeeping (~20 of ~55 slots/step)
//   - per-wave S3 sliced to 2 named regs (s3a,s3b): wave q only consumes
//     s3[k0],s3[k0+1]; full S3 output is written as disjoint slices by the
//     4 q-waves. Saves 6 FMA/step and removes runtime-indexed reg arrays.
//   - wm[k0..k0+1] read as one aligned ds_read_b64 (wave-uniform broadcast)
//   - #pragma unroll 4 (no loop-carried regs left; LDS offsets fold to imm)
// Per-step issue: ~55 -> ~35 inst (30 VALU + 5 broadcast LDS reads).
//
// Established by R0-R18 (do not revisit):
//   - 3 dispatches: 97.2 (extra ~4us dispatch gap); 1 dispatch + grid
//     barriers: 133-134 (~30us L2 writeback/invalidate per barrier)
//   - fold kernels outside the R9 shape (256 thr, sequential staged_folds,
//     <=24-reg prefetch) get VGPR-collapsed and serialize
//   - finer leaves 64x16: +6.5us; register row-prefetch in chunk: +4-6us
// Budget: ~53us harness poison-fill floor (256MiB fill @ 80% HBM peak) +
// ~12-15us dispatch gaps + kernels + tails.

#define D 8
#define LPATH 1024
#define BATCH 32
#define NCHUNK 8
#define MSTEP 128
#define SIG_STRIDE 4680
#define OFF2 8
#define OFF3 72
#define OFF4 584
#define N13F4 146  // 584 floats of levels 1-3 = 146 float4s

__device__ __forceinline__ void load8(const float* __restrict__ p, float* dst) {
  float4 lo = *(const float4*)p;
  float4 hi = *(const float4*)(p + 4);
  dst[0] = lo.x; dst[1] = lo.y; dst[2] = lo.z; dst[3] = lo.w;
  dst[4] = hi.x; dst[5] = hi.y; dst[6] = hi.z; dst[7] = hi.w;
}

__device__ __forceinline__ void store8(float* __restrict__ p, const float* src) {
  *(float4*)p       = make_float4(src[0], src[1], src[2], src[3]);
  *(float4*)(p + 4) = make_float4(src[4], src[5], src[6], src[7]);
}

// ------ Kernel 1: one block per 128-inc chunk; increments staged in LDS -----
__global__ __launch_bounds__(256) void sig_chunk128(const float* __restrict__ path,
                                                    float* __restrict__ ws) {
  __shared__ alignas(16) float wl[MSTEP * D];  // 4 KB: 128 increment rows

  const int tid  = threadIdx.x;
  const int lane = tid & 63;
  const int q    = tid >> 6;                // k-slice wave 0..3
  const int b = blockIdx.x >> 3;            // batch
  const int c = blockIdx.x & (NCHUNK - 1);  // chunk
  const int i = lane >> 3;
  const int j = lane & 7;
  const int k0 = q * 2;

  const int g0 = c * MSTEP;
  const int nrows = (129 < LPATH - g0) ? 129 : (LPATH - g0);
  const float* __restrict__ bp = path + (size_t)b * (LPATH * D) + (size_t)g0 * D;

  // Stage increments directly: thread n produces float4 n of w (row t = n>>1).
  // Rows t >= nrows-1 are the zero-increment pad (c==7 has 127 real rows).
  {
    const int n = tid;        // 0..255 covers 256 f4 = all 128 rows
    const int t = n >> 1;
    float4 w = make_float4(0.f, 0.f, 0.f, 0.f);
    if (t < nrows - 1) {
      float4 a0 = *(const float4*)(bp + 4 * n);
      float4 a1 = *(const float4*)(bp + 4 * n + D);
      w = make_float4(a1.x - a0.x, a1.y - a0.y, a1.z - a0.z, a1.w - a0.w);
    }
    *(float4*)&wl[4 * n] = w;
  }
  __syncthreads();

  float s1 = 0.f, s2 = 0.f, s3a = 0.f, s3b = 0.f;
  float s4[2][D];
#pragma unroll
  for (int t = 0; t < 2; ++t)
#pragma unroll
    for (int m = 0; m < D; ++m) s4[t][m] = 0.f;

#pragma unroll 4
  for (int t = 0; t < MSTEP; ++t) {
    float wm[D];
    *(float4*)&wm[0] = *(const float4*)&wl[t * D];
    *(float4*)&wm[4] = *(const float4*)&wl[t * D + 4];
    const float wi = wl[t * D + i];
    const float wj = wl[t * D + j];
    const float2 wk = *(const float2*)&wl[t * D + k0];  // wm[k0], wm[k0+1]

    // level-4 slice: S4 += S3(x)w + S2(x)w^2/2 + S1(x)w^3/6 + w^4/24 (Horner)
    float h1  = __builtin_fmaf(wi, 0.25f, s1);
    float h2  = __builtin_fmaf(h1, wj * (1.f / 3.f), s2);
    float hb2 = h2 * 0.5f;
    float b3a = __builtin_fmaf(hb2, wk.x, s3a);
    float b3b = __builtin_fmaf(hb2, wk.y, s3b);
#pragma unroll
    for (int m = 0; m < D; ++m) s4[0][m] = __builtin_fmaf(b3a, wm[m], s4[0][m]);
#pragma unroll
    for (int m = 0; m < D; ++m) s4[1][m] = __builtin_fmaf(b3b, wm[m], s4[1][m]);

    // level-3 slice (wave q maintains only k0,k0+1; union over waves = full S3)
    float c1 = __builtin_fmaf(wi, (1.f / 3.f), s1);
    float c2 = __builtin_fmaf(c1, wj * 0.5f, s2);
    s3a = __builtin_fmaf(c2, wk.x, s3a);
    s3b = __builtin_fmaf(c2, wk.y, s3b);

    // levels 2, 1
    float d1 = __builtin_fmaf(wi, 0.5f, s1);
    s2 = __builtin_fmaf(d1, wj, s2);
    s1 += wi;
  }

  float* __restrict__ slot = ws + (size_t)(b * NCHUNK + c) * SIG_STRIDE;
  store8(slot + OFF4 + lane * 64 + k0 * 8, s4[0]);
  store8(slot + OFF4 + lane * 64 + (k0 + 1) * 8, s4[1]);
  *(float2*)(slot + OFF3 + lane * 8 + k0) = make_float2(s3a, s3b);  // S3 slice
  if (q == 0) {
    if (j == 0) slot[i] = s1;
    slot[OFF2 + lane] = s2;
  }
}

// ---- fold from LDS levels1-3 + register B4 slice (k-sliced Chen product) ---
// Lane (i,j), slice k0: s1=S1[i], s2=S2[i][j], s3a/s3b=S3[i][j][k0..k0+1],
// s4[t][m]=S4[i][j][k0+t][m]. L = flat {S1|S2|S3} tile (584 floats).
__device__ __forceinline__ void fold_lds(const float* __restrict__ L,
                                         const float b4[2][D], float& s1,
                                         float& s2, float& s3a, float& s3b,
                                         float s4[2][D], int i, int j, int lane,
                                         int k0) {
  float b1i = L[i];
  float b1j = L[j];
  float sb1[D];
#pragma unroll
  for (int m = 0; m < D; ++m) sb1[m] = L[m];
  const float2 sb1k = *(const float2*)&L[k0];              // B1[k0], B1[k0+1]
  float b2own = L[OFF2 + lane];
  const float2 b2rj = *(const float2*)&L[OFF2 + j * 8 + k0];   // B2[j][k0..]
  const float2 b3oj = *(const float2*)&L[OFF3 + lane * 8 + k0];// B3[i][j][k0..]

  // C4 = A4 + B4 + A3[i,j,k]B1[m] + A2[i,j]B2[k,m] + A1[i]B3[j,k,m]
#pragma unroll
  for (int t = 0; t < 2; ++t) {
    const int k = k0 + t;
    float b2k[D], b3k[D];
    *(float4*)&b2k[0] = *(const float4*)&L[OFF2 + k * 8];
    *(float4*)&b2k[4] = *(const float4*)&L[OFF2 + k * 8 + 4];
    *(float4*)&b3k[0] = *(const float4*)&L[OFF3 + (j * 8 + k) * 8];
    *(float4*)&b3k[4] = *(const float4*)&L[OFF3 + (j * 8 + k) * 8 + 4];
    const float a3k = (t == 0) ? s3a : s3b;
#pragma unroll
    for (int m = 0; m < D; ++m) {
      float v = __builtin_fmaf(a3k, sb1[m], s4[t][m] + b4[t][m]);
      v = __builtin_fmaf(s2, b2k[m], v);
      s4[t][m] = __builtin_fmaf(s1, b3k[m], v);
    }
  }
  // C3 slice = A3 + B3 + A1[i]B2[j,k] + A2[i,j]B1[k]   (k in {k0, k0+1})
  s3a = __builtin_fmaf(s2, sb1k.x, __builtin_fmaf(s1, b2rj.x, s3a + b3oj.x));
  s3b = __builtin_fmaf(s2, sb1k.y, __builtin_fmaf(s1, b2rj.y, s3b + b3oj.y));
  s2 = s2 + b2own + s1 * b1j;
  s1 = s1 + b1i;
}

// Init state from sig0 at base, fold sigs 1..nsig-1. One sync per fold.
// (R9 shape - the only fold shape that keeps sane VGPR allocation.)
__device__ __forceinline__ void staged_folds(const float* __restrict__ base,
                                             int nsig, float (*lds13)[592],
                                             int tid, int i, int j, int lane,
                                             int k0, float& s1, float& s2,
                                             float& s3a, float& s3b,
                                             float s4[2][D]) {
  s1 = base[i];
  s2 = base[OFF2 + lane];
  const float2 s3i = *(const float2*)(base + OFF3 + lane * 8 + k0);
  s3a = s3i.x; s3b = s3i.y;
  load8(base + OFF4 + lane * 64 + k0 * 8, s4[0]);
  load8(base + OFF4 + lane * 64 + (k0 + 1) * 8, s4[1]);

  const float* __restrict__ B1p = base + (size_t)SIG_STRIDE;
  float b4cur[2][D];
  load8(B1p + OFF4 + lane * 64 + k0 * 8, b4cur[0]);
  load8(B1p + OFF4 + lane * 64 + (k0 + 1) * 8, b4cur[1]);
  if (tid < N13F4) {
    float4 sv = *(const float4*)(B1p + tid * 4);
    *(float4*)&lds13[1][tid * 4] = sv;
  }
  __syncthreads();

#pragma unroll 1
  for (int c = 1; c < nsig; ++c) {
    const bool more = (c + 1 < nsig);
    const float* __restrict__ Bn = base + (size_t)(c + 1) * SIG_STRIDE;
    float4 svn;
    float b4n[2][D];
    if (more) {
      if (tid < N13F4) svn = *(const float4*)(Bn + tid * 4);
      load8(Bn + OFF4 + lane * 64 + k0 * 8, b4n[0]);
      load8(Bn + OFF4 + lane * 64 + (k0 + 1) * 8, b4n[1]);
    }

    fold_lds(lds13[c & 1], b4cur, s1, s2, s3a, s3b, s4, i, j, lane, k0);

    if (more) {
      if (tid < N13F4) *(float4*)&lds13[(c + 1) & 1][tid * 4] = svn;
#pragma unroll
      for (int t = 0; t < 2; ++t)
#pragma unroll
        for (int m = 0; m < D; ++m) b4cur[t][m] = b4n[t][m];
    }
    __syncthreads();
  }
}

// ------ Kernel 2: block bb folds the 8 chunk sigs of batch bb -> d_out ------
__global__ __launch_bounds__(256) void sig_fold8f(const float* __restrict__ ws,
                                                  float* __restrict__ out) {
  __shared__ alignas(16) float lds13[2][592];
  const int tid  = threadIdx.x;
  const int q    = tid >> 6;  // k-slice wave 0..3
  const int lane = tid & 63;
  const int bb = blockIdx.x;
  const int i = lane >> 3;
  const int j = lane & 7;
  const int k0 = q * 2;

  const float* __restrict__ base = ws + (size_t)bb * NCHUNK * SIG_STRIDE;

  float s1, s2, s3a, s3b, s4[2][D];
  staged_folds(base, NCHUNK, lds13, tid, i, j, lane, k0, s1, s2, s3a, s3b, s4);

  // d_out: S1 (32x8) | S2 (32x64) | S3 (32x512) | S4 (32x4096)
  if (q == 0) {
    if (j == 0) out[bb * 8 + i] = s1;
    out[256 + bb * 64 + lane] = s2;
  }
  *(float2*)(out + 2304 + bb * 512 + lane * 8 + k0) = make_float2(s3a, s3b);
  store8(out + 18688 + bb * 4096 + lane * 64 + k0 * 8, s4[0]);
  store8(out + 18688 + bb * 4096 + lane * 64 + (k0 + 1) * 8, s4[1]);
}

extern "C" void kernel_launch(void* const* d_in, const int* in_sizes, int n_in,
                              void* d_out, int out_size, void* d_ws, size_t ws_size,
                              hipStream_t stream) {
  const float* path = (const float*)d_in[0];
  // d_in[1] = depth (==4), compile-time specialized.
  float* out = (float*)d_out;
  float* ws  = (float*)d_ws;  // 32*8*4680*4 = 4.8 MB used

  // 32 batches x 8 chunks = 256 blocks (4 q-waves each), 128 incs per chunk
  sig_chunk128<<<dim3(256), dim3(256), 0, stream>>>(path, ws);
  // 32 batches = 32 blocks; R9-shape staged fold over 8 sigs
  sig_fold8f<<<dim3(BATCH), dim3(256), 0, stream>>>(ws, out);
}